// Round 1
// baseline (716.685 us; speedup 1.0000x reference)
//
#include <hip/hip_runtime.h>
#include <hip/hip_bf16.h>

#define COLS 256          // x columns (= W columns)
#define COLS4 64          // COLS / 4 — one float4 per lane, one row per wave
#define OUTS 128          // W rows = output features
#define WAVES_PER_BLOCK 4
#define GRID_BLOCKS 1024  // 4 blocks/CU * 256 CUs -> 16 waves/CU, enough TLP for HBM

// Stage 0: zero the 256-float column-sum accumulator (ws is poisoned 0xAA each call)
__global__ void zero_kernel(float* __restrict__ s) {
    s[threadIdx.x] = 0.0f;
}

// Stage 1: s[i] = sum over rows of x[:, i]
// Each wave reads whole rows: lane l loads float4 covering columns 4l..4l+3,
// so one global_load_dwordx4 per lane = 1 KB = one full row, perfectly coalesced.
__global__ __launch_bounds__(256) void colsum_kernel(const float* __restrict__ x,
                                                     float* __restrict__ s,
                                                     int rows) {
    const int lane = threadIdx.x & 63;
    const int wave = threadIdx.x >> 6;                      // 0..3
    const int gwave = blockIdx.x * WAVES_PER_BLOCK + wave;  // global wave id
    const int nwaves = GRID_BLOCKS * WAVES_PER_BLOCK;       // total waves

    const float4* __restrict__ x4 = (const float4*)x;

    float4 acc = make_float4(0.f, 0.f, 0.f, 0.f);
    float4 acc2 = make_float4(0.f, 0.f, 0.f, 0.f);

    // 2-way unrolled grid-stride over rows for a little ILP
    int r = gwave;
    for (; r + nwaves < rows; r += 2 * nwaves) {
        float4 v0 = x4[(size_t)r * COLS4 + lane];
        float4 v1 = x4[(size_t)(r + nwaves) * COLS4 + lane];
        acc.x += v0.x; acc.y += v0.y; acc.z += v0.z; acc.w += v0.w;
        acc2.x += v1.x; acc2.y += v1.y; acc2.z += v1.z; acc2.w += v1.w;
    }
    if (r < rows) {
        float4 v0 = x4[(size_t)r * COLS4 + lane];
        acc.x += v0.x; acc.y += v0.y; acc.z += v0.z; acc.w += v0.w;
    }
    acc.x += acc2.x; acc.y += acc2.y; acc.z += acc2.z; acc.w += acc2.w;

    // Reduce the block's 4 waves in LDS, then one atomicAdd per column per block.
    __shared__ float4 sm[WAVES_PER_BLOCK][COLS4];
    sm[wave][lane] = acc;
    __syncthreads();
    if (wave == 0) {
        float4 t = sm[0][lane];
        #pragma unroll
        for (int w = 1; w < WAVES_PER_BLOCK; ++w) {
            float4 u = sm[w][lane];
            t.x += u.x; t.y += u.y; t.z += u.z; t.w += u.w;
        }
        atomicAdd(&s[lane * 4 + 0], t.x);
        atomicAdd(&s[lane * 4 + 1], t.y);
        atomicAdd(&s[lane * 4 + 2], t.z);
        atomicAdd(&s[lane * 4 + 3], t.w);
    }
}

// Stage 2: h[o] = sum_i s[i] * W[o, i]  (tiny: 128 KB of W, one block)
__global__ void proj_kernel(const float* __restrict__ s,
                            const float* __restrict__ W,
                            float* __restrict__ out) {
    __shared__ float sl[COLS];
    sl[threadIdx.x] = s[threadIdx.x];
    __syncthreads();
    if (threadIdx.x < OUTS) {
        const float4* __restrict__ w4 = (const float4*)(W + threadIdx.x * COLS);
        const float4* __restrict__ s4 = (const float4*)sl;
        float acc = 0.f;
        #pragma unroll
        for (int i = 0; i < COLS4; ++i) {
            float4 w = w4[i];
            float4 v = s4[i];
            acc += w.x * v.x + w.y * v.y + w.z * v.z + w.w * v.w;
        }
        out[threadIdx.x] = acc;
    }
}

extern "C" void kernel_launch(void* const* d_in, const int* in_sizes, int n_in,
                              void* d_out, int out_size, void* d_ws, size_t ws_size,
                              hipStream_t stream) {
    const float* x = (const float*)d_in[0];   // [rows, 256] fp32
    const float* W = (const float*)d_in[1];   // [128, 256] fp32
    float* out = (float*)d_out;               // [128] fp32
    float* s = (float*)d_ws;                  // 256 floats of scratch

    const int rows = in_sizes[0] / COLS;      // 500000

    zero_kernel<<<1, COLS, 0, stream>>>(s);
    colsum_kernel<<<GRID_BLOCKS, 256, 0, stream>>>(x, s, rows);
    proj_kernel<<<1, COLS, 0, stream>>>(s, W, out);
}

// Round 2
// 702.736 us; speedup vs baseline: 1.0198x; 1.0198x over previous
//
#include <hip/hip_runtime.h>
#include <hip/hip_bf16.h>

#define COLS 256          // x columns (= W columns)
#define COLS4 64          // COLS / 4 — one float4 per lane, one row per wave
#define OUTS 128          // W rows = output features
#define WAVES_PER_BLOCK 4
#define GRID_BLOCKS 1024  // 4 blocks/CU * 256 CUs -> 16 waves/CU

__device__ __forceinline__ void facc(float4& a, const float4& v) {
    a.x += v.x; a.y += v.y; a.z += v.z; a.w += v.w;
}

// Stage 0: zero the 256-float column-sum accumulator (ws is poisoned 0xAA each call)
__global__ void zero_kernel(float* __restrict__ s) {
    s[threadIdx.x] = 0.0f;
}

// Stage 1: s[i] = sum over rows of x[:, i]
// Each wave owns a CONTIGUOUS chunk of rows and streams it sequentially:
// lane l loads the float4 at columns 4l..4l+3 of row r (one dwordx4 per lane,
// 1 KB per wave-instruction, perfectly coalesced). Unroll x8 keeps 8
// independent loads in flight per wave from one running pointer.
__global__ __launch_bounds__(256) void colsum_kernel(const float* __restrict__ x,
                                                     float* __restrict__ s,
                                                     int rows) {
    const int lane = threadIdx.x & 63;
    const int wave = threadIdx.x >> 6;                      // 0..3
    const int gwave = blockIdx.x * WAVES_PER_BLOCK + wave;  // global wave id
    const int nwaves = GRID_BLOCKS * WAVES_PER_BLOCK;       // 4096

    const int rpw = (rows + nwaves - 1) / nwaves;           // rows per wave (123)
    int r = gwave * rpw;
    int rend = r + rpw;
    if (rend > rows) rend = rows;

    const float4* __restrict__ p = (const float4*)x + (size_t)r * COLS4 + lane;

    float4 a0 = make_float4(0.f, 0.f, 0.f, 0.f);
    float4 a1 = make_float4(0.f, 0.f, 0.f, 0.f);
    float4 a2 = make_float4(0.f, 0.f, 0.f, 0.f);
    float4 a3 = make_float4(0.f, 0.f, 0.f, 0.f);

    // 8 rows per iteration: 8 independent dwordx4 loads in flight.
    for (; r + 8 <= rend; r += 8, p += 8 * COLS4) {
        float4 v0 = p[0 * COLS4];
        float4 v1 = p[1 * COLS4];
        float4 v2 = p[2 * COLS4];
        float4 v3 = p[3 * COLS4];
        float4 v4 = p[4 * COLS4];
        float4 v5 = p[5 * COLS4];
        float4 v6 = p[6 * COLS4];
        float4 v7 = p[7 * COLS4];
        facc(a0, v0); facc(a1, v1); facc(a2, v2); facc(a3, v3);
        facc(a0, v4); facc(a1, v5); facc(a2, v6); facc(a3, v7);
    }
    for (; r < rend; ++r, p += COLS4) {
        float4 v = p[0];
        facc(a0, v);
    }
    facc(a0, a1); facc(a2, a3); facc(a0, a2);

    // Reduce the block's 4 waves in LDS, then one atomicAdd per column per block.
    __shared__ float4 sm[WAVES_PER_BLOCK][COLS4];
    sm[wave][lane] = a0;
    __syncthreads();
    if (wave == 0) {
        float4 t = sm[0][lane];
        #pragma unroll
        for (int w = 1; w < WAVES_PER_BLOCK; ++w) facc(t, sm[w][lane]);
        atomicAdd(&s[lane * 4 + 0], t.x);
        atomicAdd(&s[lane * 4 + 1], t.y);
        atomicAdd(&s[lane * 4 + 2], t.z);
        atomicAdd(&s[lane * 4 + 3], t.w);
    }
}

// Stage 2: h[o] = sum_i s[i] * W[o, i]  (tiny: 128 KB of W, one block)
__global__ void proj_kernel(const float* __restrict__ s,
                            const float* __restrict__ W,
                            float* __restrict__ out) {
    __shared__ float sl[COLS];
    sl[threadIdx.x] = s[threadIdx.x];
    __syncthreads();
    if (threadIdx.x < OUTS) {
        const float4* __restrict__ w4 = (const float4*)(W + threadIdx.x * COLS);
        const float4* __restrict__ s4 = (const float4*)sl;
        float acc = 0.f;
        #pragma unroll
        for (int i = 0; i < COLS4; ++i) {
            float4 w = w4[i];
            float4 v = s4[i];
            acc += w.x * v.x + w.y * v.y + w.z * v.z + w.w * v.w;
        }
        out[threadIdx.x] = acc;
    }
}

extern "C" void kernel_launch(void* const* d_in, const int* in_sizes, int n_in,
                              void* d_out, int out_size, void* d_ws, size_t ws_size,
                              hipStream_t stream) {
    const float* x = (const float*)d_in[0];   // [rows, 256] fp32
    const float* W = (const float*)d_in[1];   // [128, 256] fp32
    float* out = (float*)d_out;               // [128] fp32
    float* s = (float*)d_ws;                  // 256 floats of scratch

    const int rows = in_sizes[0] / COLS;      // 500000

    zero_kernel<<<1, COLS, 0, stream>>>(s);
    colsum_kernel<<<GRID_BLOCKS, 256, 0, stream>>>(x, s, rows);
    proj_kernel<<<1, COLS, 0, stream>>>(s, W, out);
}